// Round 11
// baseline (10546.048 us; speedup 1.0000x reference)
//
#include <hip/hip_runtime.h>
#include <cmath>

#define BB 64
#define TT 512
#define II 256
#define HH 1024
#define OO 512
#define CHK 2112                         // 2048B chunk data + 64B footer line
#define H1SLOT (32 * CHK)                // one (slot,group) h1 buffer: 32 chunks
#define H2SLOT (32 * CHK)

typedef short bf8 __attribute__((ext_vector_type(8)));    // 8 bf16 vals
typedef float f32x4 __attribute__((ext_vector_type(4)));
typedef unsigned long long u64;

#define MFMA(a, b, c) __builtin_amdgcn_mfma_f32_16x16x32_bf16((a), (b), (c), 0, 0, 0)

__device__ __forceinline__ unsigned short f2bf(float f) {
    unsigned u = __float_as_uint(f);
    return (unsigned short)((u + 0x7fffu + ((u >> 16) & 1u)) >> 16);
}
__device__ __forceinline__ float bf2f(unsigned short h) {
    return __uint_as_float((unsigned)h << 16);
}
__device__ __forceinline__ void split8(const float* v, bf8& hi, bf8& lo) {
#pragma unroll
    for (int j = 0; j < 8; ++j) {
        unsigned short h = f2bf(v[j]);
        float r = v[j] - bf2f(h);
        hi[j] = (short)h;
        lo[j] = (short)f2bf(r);
    }
}
__device__ __forceinline__ void ld8(float* v, const float* p) {
    *(float4*)v       = *(const float4*)p;
    *(float4*)(v + 4) = *(const float4*)(p + 4);
}

// h data loads: PLAIN CACHED (L1+L2 allocate -> concurrent same-line misses
// merge in L2). Freshness guaranteed by the acquire fence (buffer_inv sc1)
// issued after the footer poll, before these loads.
__device__ __forceinline__ bf8 load_h(const void* p) {
    return *(const bf8*)p;
}
// Producer stores stay on the proven sc1 write-through path (R6-R10).
__device__ __forceinline__ void store16(void* p, u64 a, u64 b) {
    __hip_atomic_store((u64*)p, a, __ATOMIC_RELAXED, __HIP_MEMORY_SCOPE_AGENT);
    __hip_atomic_store((u64*)((char*)p + 8), b, __ATOMIC_RELAXED, __HIP_MEMORY_SCOPE_AGENT);
}
// Footer polls must stay UNCACHED (atomic relaxed agent): a cached poll could
// spin forever on a stale L1 line.
__device__ __forceinline__ unsigned ld_flag(const void* p) {
    return __hip_atomic_load((const unsigned*)p, __ATOMIC_RELAXED, __HIP_MEMORY_SCOPE_AGENT);
}
__device__ __forceinline__ void st_flag(void* p, unsigned v) {
    __hip_atomic_store((unsigned*)p, v, __ATOMIC_RELAXED, __HIP_MEMORY_SCOPE_AGENT);
}
// Acquire fence: invalidates stale L1/L2 (buffer_inv sc1 on CDNA3/4) so the
// plain cached loads below observe at-least-L3-fresh data.
__device__ __forceinline__ void acquire_fence() {
    __builtin_amdgcn_fence(__ATOMIC_ACQUIRE, "agent");
    asm volatile("" ::: "memory");
}

// Layout / schedule identical to R10:
// h chunk c of (layer,grp): 64 lanes x 32B data at c*CHK + lane*32, footer u32
// at c*CHK + 2048. Footer = t+1 after producer's step t.
// Grid 256 x 512: grp=bid&3 (16 batches), layer=(bid>>2)&1, slot=bid>>3 (32 rows).
// L0@t: h1(t) = tanh(x(t)@Wih0^T + b + h1(t-1)@Whh0^T)        [t=0..TT-1]
// L1@t: h2(t-1) = tanh(h1(t-1)@Wih1^T + b + h2(t-2)@Whh1^T)   [t=1..TT]
// Waves poll their own 8 chunk footers, fence, then plain-load h.
__global__ __launch_bounds__(512, 2) void rnn_cache(
    const float* __restrict__ x,
    const float* __restrict__ Wih0, const float* __restrict__ Whh0,
    const float* __restrict__ bih0, const float* __restrict__ bhh0,
    const float* __restrict__ Wih1, const float* __restrict__ Whh1,
    const float* __restrict__ bih1, const float* __restrict__ bhh1,
    const float* __restrict__ Wfc,  const float* __restrict__ bfc,
    float* __restrict__ out, float* __restrict__ ws)
{
    __shared__ float shmem[4864];          // ps [8][2][16][17]=4352 | staging 512 fl
    float* ps = shmem;
    char*  staging = (char*)(shmem + 4352);

    const int tid  = threadIdx.x;
    const int w    = tid >> 6;
    const int lane = tid & 63;
    const int col  = lane & 15;
    const int kg   = lane >> 4;
    const int bid  = blockIdx.x;
    const int grp   = bid & 3;
    const int layer = (bid >> 2) & 1;
    const int slot  = bid >> 3;            // 0..31
    const int rb    = slot * 32;
    const int b0    = grp * 16;

    char* wsB    = (char*)ws;
    char* h1base = wsB;                    // [4 slots][4 grp] * H1SLOT
    char* h2base = wsB + 16 * H1SLOT;      // [2 slots][4 grp] * H2SLOT

    // ---- weight preload into VGPRs (once) — identical to R9/R10 ----
    bf8 wxh[2], wxl[2];                    // L0: Wih0
    bf8 wah[2][4], wal[2][4];              // L0: Whh0 | L1: Wih1
    bf8 wbh[2][4], wbl[2][4];              // L1: Whh1
    {
        float v[8];
        if (layer == 0) {
            #pragma unroll
            for (int n = 0; n < 2; ++n) {
                ld8(v, Wih0 + (size_t)(rb + n * 16 + col) * II + (w * 32 + kg * 8));
                split8(v, wxh[n], wxl[n]);
                #pragma unroll
                for (int c = 0; c < 4; ++c) {
                    ld8(v, Whh0 + (size_t)(rb + n * 16 + col) * HH + (w * 128 + c * 32 + kg * 8));
                    split8(v, wah[n][c], wal[n][c]);
                }
            }
        } else {
            #pragma unroll
            for (int n = 0; n < 2; ++n)
                #pragma unroll
                for (int c = 0; c < 4; ++c) {
                    ld8(v, Wih1 + (size_t)(rb + n * 16 + col) * HH + (w * 128 + c * 32 + kg * 8));
                    split8(v, wah[n][c], wal[n][c]);
                    ld8(v, Whh1 + (size_t)(rb + n * 16 + col) * HH + (w * 128 + c * 32 + kg * 8));
                    split8(v, wbh[n][c], wbl[n][c]);
                }
        }
    }

    // ---- epilogue role constants ----
    const int ekk = tid >> 4;              // 0..31 (row within WG's chunk)
    const int eb  = tid & 15;              // batch
    const int R   = rb + ekk;
    const float bsum = layer ? (bih1[R] + bhh1[R]) : (bih0[R] + bhh0[R]);
    const int stg_off = (eb + 16 * (ekk >> 3)) * 32 + (ekk & 7) * 2;

    const int tBeg = layer ? 1 : 0;
    const int tEnd = layer ? TT : TT - 1;

    for (int t = tBeg; t <= tEnd; ++t) {
        const char* h1r = h1base + (size_t)(((t - 1) & 3) * 4 + grp) * H1SLOT;
        const char* h2s = h2base + (size_t)((t & 1) * 4 + grp) * H2SLOT; // (t-2)&1 == t&1

        // ---- x prefetch (before poll; input-static) ----
        float xv[8];
        if (layer == 0)
            ld8(xv, x + ((size_t)(b0 + col) * TT + t) * II + (w * 32 + kg * 8));
        asm volatile("" ::: "memory");

        // ---- per-wave poll on the 8 chunk footers this wave touches ----
        {
            const int pc = lane & 3;
            bool active = false; unsigned tgt = 0; bool ge = false;
            const char* fp = h1r + 2048;   // placeholder
            if (lane < 4) {                // h1(t-1) chunks: footer == t
                active = (t >= 1); tgt = (unsigned)t; ge = false;
                fp = h1r + (size_t)(w * 4 + pc) * CHK + 2048;
            } else if (lane < 8) {         // h2 chunks
                fp = h2s + (size_t)(w * 4 + pc) * CHK + 2048;
                if (layer == 0) { active = (t >= 4); tgt = (unsigned)(t - 2); ge = true;  }
                else            { active = (t >= 2); tgt = (unsigned)t;       ge = false; }
            }
            if (__any(active ? 1 : 0)) {
                for (;;) {
                    bool ok = true;
                    if (active) {
                        unsigned f = ld_flag(fp);
                        ok = ge ? (f >= tgt) : (f == tgt);
                    }
                    if (__all(ok ? 1 : 0)) break;
                    __builtin_amdgcn_s_sleep(1);
                }
            }
        }
        // invalidate stale L1/L2 before the plain cached h loads
        acquire_fence();

        f32x4 acc0 = {0.f, 0.f, 0.f, 0.f};
        f32x4 acc1 = {0.f, 0.f, 0.f, 0.f};

        if (layer == 0) {
            bf8 xh, xl;
            split8(xv, xh, xl);
            bf8 hh[4], hl[4];
            if (t >= 1) {
                #pragma unroll
                for (int c = 0; c < 4; ++c) {
                    const char* p = h1r + (size_t)(w * 4 + c) * CHK + lane * 32;
                    hh[c] = load_h(p); hl[c] = load_h(p + 16);
                }
            }
            acc0 = MFMA(xh, wxh[0], acc0); acc0 = MFMA(xh, wxl[0], acc0); acc0 = MFMA(xl, wxh[0], acc0);
            acc1 = MFMA(xh, wxh[1], acc1); acc1 = MFMA(xh, wxl[1], acc1); acc1 = MFMA(xl, wxh[1], acc1);
            if (t >= 1) {
                #pragma unroll
                for (int c = 0; c < 4; ++c) {
                    acc0 = MFMA(hh[c], wah[0][c], acc0); acc0 = MFMA(hh[c], wal[0][c], acc0);
                    acc0 = MFMA(hl[c], wah[0][c], acc0);
                    acc1 = MFMA(hh[c], wah[1][c], acc1); acc1 = MFMA(hh[c], wal[1][c], acc1);
                    acc1 = MFMA(hl[c], wah[1][c], acc1);
                }
            }
        } else {
            bf8 hh[4], hl[4], gh[4], gl[4];
            #pragma unroll
            for (int c = 0; c < 4; ++c) {
                const char* p = h1r + (size_t)(w * 4 + c) * CHK + lane * 32;
                hh[c] = load_h(p); hl[c] = load_h(p + 16);
            }
            if (t >= 2) {
                #pragma unroll
                for (int c = 0; c < 4; ++c) {
                    const char* p = h2s + (size_t)(w * 4 + c) * CHK + lane * 32;
                    gh[c] = load_h(p); gl[c] = load_h(p + 16);
                }
            }
            #pragma unroll
            for (int c = 0; c < 4; ++c) {
                acc0 = MFMA(hh[c], wah[0][c], acc0); acc0 = MFMA(hh[c], wal[0][c], acc0);
                acc0 = MFMA(hl[c], wah[0][c], acc0);
                acc1 = MFMA(hh[c], wah[1][c], acc1); acc1 = MFMA(hh[c], wal[1][c], acc1);
                acc1 = MFMA(hl[c], wah[1][c], acc1);
            }
            if (t >= 2) {
                #pragma unroll
                for (int c = 0; c < 4; ++c) {
                    acc0 = MFMA(gh[c], wbh[0][c], acc0); acc0 = MFMA(gh[c], wbl[0][c], acc0);
                    acc0 = MFMA(gl[c], wbh[0][c], acc0);
                    acc1 = MFMA(gh[c], wbh[1][c], acc1); acc1 = MFMA(gh[c], wbl[1][c], acc1);
                    acc1 = MFMA(gl[c], wbh[1][c], acc1);
                }
            }
        }

        // ---- partials to LDS ----
        {
            float* pw = ps + w * 544;
            #pragma unroll
            for (int r = 0; r < 4; ++r) {
                pw[(kg * 4 + r) * 17 + col]       = acc0[r];
                pw[272 + (kg * 4 + r) * 17 + col] = acc1[r];
            }
        }
        __syncthreads();

        // ---- reduce + bias + tanh + hi/lo split -> LDS staging ----
        {
            float s = bsum;
            #pragma unroll
            for (int wv = 0; wv < 8; ++wv)
                s += ps[wv * 544 + (ekk >> 4) * 272 + eb * 17 + (ekk & 15)];
            const float val = tanhf(s);
            const unsigned short hi = f2bf(val);
            const unsigned short lo = f2bf(val - bf2f(hi));
            *(unsigned short*)(staging + stg_off)      = hi;
            *(unsigned short*)(staging + stg_off + 16) = lo;
        }
        __syncthreads();

        // ---- coalesced chunk store (128 x 16B, sc1) + footer publish ----
        char* hw = layer
            ? (h2base + (size_t)(((t - 1) & 1) * 4 + grp) * H2SLOT)
            : (h1base + (size_t)((t & 3) * 4 + grp) * H1SLOT);
        if (tid < 128) {
            const int off = (tid >> 1) * 32 + (tid & 1) * 16;
            const char* src = staging + off;
            store16(hw + (size_t)slot * CHK + off,
                    *(const u64*)src, *(const u64*)(src + 8));
        }
        asm volatile("s_waitcnt vmcnt(0)" ::: "memory");
        __syncthreads();
        if (tid == 0)
            st_flag(hw + (size_t)slot * CHK + 2048, (unsigned)(t + 1));
    }

    // ---- FC gate: all 128 h2 slot-1 chunk footers == TT+1 ----
    if (tid < 128) {
        const char* fp = h2base + (size_t)(4 + (tid >> 5)) * H2SLOT
                       + (size_t)(tid & 31) * CHK + 2048;
        while (ld_flag(fp) != (unsigned)(TT + 1))
            __builtin_amdgcn_s_sleep(2);
    }
    __syncthreads();
    acquire_fence();

    // ---- FC: block computes out[:, 2*bid .. 2*bid+1] ----
    float* Wlds = shmem + 2304;
    ((float4*)Wlds)[tid] = ((const float4*)(Wfc + (size_t)(2 * bid) * HH))[tid];
    __syncthreads();

    float p0 = 0.f, p1 = 0.f;
    {
        const int gr = lane >> 4, bsub = lane & 15;
        const char* hb = h2base + (size_t)(4 + gr) * H2SLOT;   // slot 1 = (TT-1)&1
        #pragma unroll 4
        for (int k8 = w * 16; k8 < w * 16 + 16; ++k8) {
            const char* p = hb + (size_t)(k8 >> 2) * CHK
                          + (size_t)(bsub + ((k8 & 3) << 4)) * 32;
            bf8 hi = load_h(p), lo = load_h(p + 16);
            const int kb = k8 * 8;
            #pragma unroll
            for (int j = 0; j < 8; ++j) {
                float f = bf2f((unsigned short)hi[j]) + bf2f((unsigned short)lo[j]);
                p0 += f * Wlds[kb + j];
                p1 += f * Wlds[1024 + kb + j];
            }
        }
    }
    __syncthreads();
    shmem[(w * 64 + lane) * 2 + 0] = p0;
    shmem[(w * 64 + lane) * 2 + 1] = p1;
    __syncthreads();
    if (w < 2) {
        float s = bfc[2 * bid + w];
        #pragma unroll
        for (int j = 0; j < 8; ++j) s += shmem[(j * 64 + lane) * 2 + w];
        out[(size_t)lane * OO + 2 * bid + w] = s;
    }
}

extern "C" void kernel_launch(void* const* d_in, const int* in_sizes, int n_in,
                              void* d_out, int out_size, void* d_ws, size_t ws_size,
                              hipStream_t stream) {
    const float* x    = (const float*)d_in[0];
    const float* Wih0 = (const float*)d_in[1];
    const float* Whh0 = (const float*)d_in[2];
    const float* bih0 = (const float*)d_in[3];
    const float* bhh0 = (const float*)d_in[4];
    const float* Wih1 = (const float*)d_in[5];
    const float* Whh1 = (const float*)d_in[6];
    const float* bih1 = (const float*)d_in[7];
    const float* bhh1 = (const float*)d_in[8];
    const float* Wfc  = (const float*)d_in[9];
    const float* bfc  = (const float*)d_in[10];
    float* out = (float*)d_out;
    float* ws  = (float*)d_ws;

    // zero the whole h region (footers included) every call — replay-safe.
    const size_t hbytes = (size_t)16 * H1SLOT + (size_t)8 * H2SLOT;  // ~1.6 MB
    hipMemsetAsync(d_ws, 0, hbytes, stream);

    void* args[] = { (void*)&x,
                     (void*)&Wih0, (void*)&Whh0, (void*)&bih0, (void*)&bhh0,
                     (void*)&Wih1, (void*)&Whh1, (void*)&bih1, (void*)&bhh1,
                     (void*)&Wfc,  (void*)&bfc,  (void*)&out,  (void*)&ws };
    hipLaunchCooperativeKernel((void*)rnn_cache, dim3(256), dim3(512),
                               args, 0, stream);
}

// Round 12
// 3998.952 us; speedup vs baseline: 2.6372x; 2.6372x over previous
//
#include <hip/hip_runtime.h>
#include <cmath>

#define BB 64
#define TT 512
#define II 256
#define HH 1024
#define OO 512
#define NSLOT 32                          // h ring depth (slot = t & 31)

typedef short bf8 __attribute__((ext_vector_type(8)));    // 8 bf16 vals
typedef float f32x4 __attribute__((ext_vector_type(4)));
typedef unsigned long long u64;

#define MFMA(a, b, c) __builtin_amdgcn_mfma_f32_16x16x32_bf16((a), (b), (c), 0, 0, 0)

__device__ __forceinline__ unsigned short f2bf(float f) {
    unsigned u = __float_as_uint(f);
    return (unsigned short)((u + 0x7fffu + ((u >> 16) & 1u)) >> 16);
}
__device__ __forceinline__ float bf2f(unsigned short h) {
    return __uint_as_float((unsigned)h << 16);
}
__device__ __forceinline__ void split8(const float* v, bf8& hi, bf8& lo) {
#pragma unroll
    for (int j = 0; j < 8; ++j) {
        unsigned short h = f2bf(v[j]);
        float r = v[j] - bf2f(h);
        hi[j] = (short)h;
        lo[j] = (short)f2bf(r);
    }
}

// Consumer h loads: PLAIN CACHED (L1+L2). The ~32 WGs/XCD reading the same
// group-h line merge in L2 -> ~1 L3 fill per XCD instead of 64 sc1 requests.
// Freshness: depth-32 slot ring + acquire fence every 16 intervals (see proof
// in round notes); R11 proved the fence+cached-load path is coherence-correct.
__device__ __forceinline__ bf8 load_h(const void* p) {
    return *(const bf8*)p;
}
// Producer stores stay on the proven sc1 write-through path (R6-R11).
__device__ __forceinline__ void store_h16(void* p, u64 a, u64 b) {
    __hip_atomic_store((u64*)p, a, __ATOMIC_RELAXED, __HIP_MEMORY_SCOPE_AGENT);
    __hip_atomic_store((u64*)((char*)p + 8), b, __ATOMIC_RELAXED, __HIP_MEMORY_SCOPE_AGENT);
}
// Flag polls stay UNCACHED (relaxed agent atomics).
__device__ __forceinline__ unsigned ld_flag(const void* p) {
    return __hip_atomic_load((const unsigned*)p, __ATOMIC_RELAXED, __HIP_MEMORY_SCOPE_AGENT);
}
__device__ __forceinline__ void st_flag(void* p, unsigned v) {
    __hip_atomic_store((unsigned*)p, v, __ATOMIC_RELAXED, __HIP_MEMORY_SCOPE_AGENT);
}
__device__ __forceinline__ void acquire_fence() {
    __builtin_amdgcn_fence(__ATOMIC_ACQUIRE, "agent");
    asm volatile("" ::: "memory");
}

// h fragment layout per (layer, slot, group) 64KB buffer: 32 K-chunks x 64
// lanes x (16B hi + 16B lo). Element h[b][k]: chunk k>>5, lane
// (b&15)+16*((k&31)>>3), j=k&7: hi j*2, lo j*2+16.
//
// Grid 256 x 512 (R8 structure). group = blockIdx&3 (batches grp*16..+15),
// cu = blockIdx>>2 (rows cu*16..+15 of BOTH layers).
// Waves 0-3: L0 tile; waves 4-7: L1 tile. Interval t: h1(t) and h2(t-1).
// Flag array: flag[grp*64+cu] (16B spread) = t+1 after interval t; wave 0
// polls its group's 64 flags. Monolithic barrier -> skew <= 1 interval.
__global__ __launch_bounds__(512, 2) void rnn_ring(
    const float* __restrict__ x,
    const float* __restrict__ Wih0, const float* __restrict__ Whh0,
    const float* __restrict__ bih0, const float* __restrict__ bhh0,
    const float* __restrict__ Wih1, const float* __restrict__ Whh1,
    const float* __restrict__ bih1, const float* __restrict__ bhh1,
    const float* __restrict__ Wfc,  const float* __restrict__ bfc,
    float* __restrict__ out, float* __restrict__ ws)
{
    const int tid  = threadIdx.x;
    const int w    = tid >> 6;      // wave 0..7
    const int lane = tid & 63;
    const int col  = lane & 15;
    const int kg   = lane >> 4;
    const int grp  = blockIdx.x & 3;
    const int cu   = blockIdx.x >> 2;
    const int rb   = cu * 16;
    const int b0   = grp * 16;

    __shared__ float shmem[4224];   // Ps [8][16][17] = 2176 | Wlds 2048

    char* wsB = (char*)ws;
    // flags: [grp*64+cu]*16B, 4KB total
    char* h1base = wsB + 4096;                              // [32 slot][4 grp] 64KB = 8MB
    char* h2base = h1base + (size_t)NSLOT * 4 * 65536;      // [32 slot][4 grp] 64KB = 8MB

    // ---- preload weight B-fragments into registers (once) — identical R8 ----
    bf8 wreg[32];
    if (w < 4) {
        #pragma unroll
        for (int c = 0; c < 2; ++c) {
            const float* p = Wih0 + (size_t)(rb + col) * II + (w * 64 + c * 32 + kg * 8);
            float v[8];
            *(float4*)v       = *(const float4*)p;
            *(float4*)(v + 4) = *(const float4*)(p + 4);
            split8(v, wreg[2 * c], wreg[2 * c + 1]);
        }
        #pragma unroll
        for (int c = 0; c < 8; ++c) {
            const float* p = Whh0 + (size_t)(rb + col) * HH + (w * 256 + c * 32 + kg * 8);
            float v[8];
            *(float4*)v       = *(const float4*)p;
            *(float4*)(v + 4) = *(const float4*)(p + 4);
            split8(v, wreg[4 + 2 * c], wreg[5 + 2 * c]);
        }
    } else {
        const int w4 = w - 4;
        #pragma unroll
        for (int c = 0; c < 8; ++c) {
            const float* p = Wih1 + (size_t)(rb + col) * HH + (w4 * 256 + c * 32 + kg * 8);
            float v[8];
            *(float4*)v       = *(const float4*)p;
            *(float4*)(v + 4) = *(const float4*)(p + 4);
            split8(v, wreg[2 * c], wreg[2 * c + 1]);
        }
        #pragma unroll
        for (int c = 0; c < 8; ++c) {
            const float* p = Whh1 + (size_t)(rb + col) * HH + (w4 * 256 + c * 32 + kg * 8);
            float v[8];
            *(float4*)v       = *(const float4*)p;
            *(float4*)(v + 4) = *(const float4*)(p + 4);
            split8(v, wreg[16 + 2 * c], wreg[17 + 2 * c]);
        }
    }

    // ---- epilogue role constants — identical R8 ----
    const int side = tid >> 8;
    const int u    = tid & 255;
    const int eb   = u & 15;
    const int ekk  = u >> 4;
    const float bsum = (side == 0) ? (bih0[rb + ekk] + bhh0[rb + ekk])
                                   : (bih1[rb + ekk] + bhh1[rb + ekk]);
    const int Rk   = rb + ekk;
    const size_t eoff = (size_t)(Rk >> 5) * 2048
                      + (size_t)(eb + (((Rk & 31) >> 3) << 4)) * 32
                      + (size_t)(Rk & 7) * 2;

    acquire_fence();   // kill stale lines from a previous graph replay

    for (int t = 0; t <= TT; ++t) {
        // periodic invalidate: any slot rewrite (period 32) has >=2 fences
        // between its two consumer epochs; skew <=1 step keeps this safe.
        if ((t & 15) == 0) acquire_fence();

        f32x4 acc0 = {0.f, 0.f, 0.f, 0.f};
        f32x4 acc1 = {0.f, 0.f, 0.f, 0.f};

        const char* h1r = h1base + (size_t)(((t - 1) & (NSLOT - 1)) * 4 + grp) * 65536;
        const char* h2r = h2base + (size_t)(((t - 2) & (NSLOT - 1)) * 4 + grp) * 65536;

        if (w < 4) {
            if (t < TT) {
                const float* xb = x + ((size_t)(b0 + col) * TT + t) * II + (w * 64 + kg * 8);
                float v[8];
                bf8 ahi, alo;
                *(float4*)v       = *(const float4*)xb;
                *(float4*)(v + 4) = *(const float4*)(xb + 4);
                split8(v, ahi, alo);
                acc0 = MFMA(ahi, wreg[0], acc0);
                acc0 = MFMA(ahi, wreg[1], acc0);
                acc0 = MFMA(alo, wreg[0], acc0);
                *(float4*)v       = *(const float4*)(xb + 32);
                *(float4*)(v + 4) = *(const float4*)(xb + 36);
                split8(v, ahi, alo);
                acc1 = MFMA(ahi, wreg[2], acc1);
                acc1 = MFMA(ahi, wreg[3], acc1);
                acc1 = MFMA(alo, wreg[2], acc1);
                if (t > 0) {
                    const char* hb = h1r + (size_t)(w * 8) * 2048 + lane * 32;
                    #pragma unroll
                    for (int c = 0; c < 8; ++c) {
                        bf8 hhi = load_h(hb + c * 2048);
                        bf8 hlo = load_h(hb + c * 2048 + 16);
                        if (c & 1) {
                            acc1 = MFMA(hhi, wreg[4 + 2 * c], acc1);
                            acc1 = MFMA(hhi, wreg[5 + 2 * c], acc1);
                            acc1 = MFMA(hlo, wreg[4 + 2 * c], acc1);
                        } else {
                            acc0 = MFMA(hhi, wreg[4 + 2 * c], acc0);
                            acc0 = MFMA(hhi, wreg[5 + 2 * c], acc0);
                            acc0 = MFMA(hlo, wreg[4 + 2 * c], acc0);
                        }
                    }
                }
            }
        } else {
            if (t >= 1) {
                const int w4 = w - 4;
                const char* hb = h1r + (size_t)(w4 * 8) * 2048 + lane * 32;
                #pragma unroll
                for (int c = 0; c < 8; ++c) {
                    bf8 hhi = load_h(hb + c * 2048);
                    bf8 hlo = load_h(hb + c * 2048 + 16);
                    if (c & 1) {
                        acc1 = MFMA(hhi, wreg[2 * c], acc1);
                        acc1 = MFMA(hhi, wreg[2 * c + 1], acc1);
                        acc1 = MFMA(hlo, wreg[2 * c], acc1);
                    } else {
                        acc0 = MFMA(hhi, wreg[2 * c], acc0);
                        acc0 = MFMA(hhi, wreg[2 * c + 1], acc0);
                        acc0 = MFMA(hlo, wreg[2 * c], acc0);
                    }
                }
                if (t >= 2) {
                    const char* hb2 = h2r + (size_t)(w4 * 8) * 2048 + lane * 32;
                    #pragma unroll
                    for (int c = 0; c < 8; ++c) {
                        bf8 hhi = load_h(hb2 + c * 2048);
                        bf8 hlo = load_h(hb2 + c * 2048 + 16);
                        if (c & 1) {
                            acc1 = MFMA(hhi, wreg[16 + 2 * c], acc1);
                            acc1 = MFMA(hhi, wreg[17 + 2 * c], acc1);
                            acc1 = MFMA(hlo, wreg[16 + 2 * c], acc1);
                        } else {
                            acc0 = MFMA(hhi, wreg[16 + 2 * c], acc0);
                            acc0 = MFMA(hhi, wreg[17 + 2 * c], acc0);
                            acc0 = MFMA(hlo, wreg[16 + 2 * c], acc0);
                        }
                    }
                }
            }
        }

        // ---- write partial tiles ----
        {
            f32x4 s4 = acc0 + acc1;
            #pragma unroll
            for (int r = 0; r < 4; ++r)
                shmem[(w * 16 + kg * 4 + r) * 17 + col] = s4[r];
        }
        __syncthreads();

        // ---- epilogue: reduce, bias, tanh, split, sc1 store ----
        {
            const bool doit = (side == 0) ? (t < TT) : (t >= 1);
            if (doit) {
                const int wb = side * 4;
                float s = shmem[((wb + 0) * 16 + eb) * 17 + ekk]
                        + shmem[((wb + 1) * 16 + eb) * 17 + ekk]
                        + shmem[((wb + 2) * 16 + eb) * 17 + ekk]
                        + shmem[((wb + 3) * 16 + eb) * 17 + ekk];
                s += bsum;
                const float val = tanhf(s);
                const unsigned short hi = f2bf(val);
                const unsigned short lo = f2bf(val - bf2f(hi));
                char* wp = (side
                    ? (h2base + (size_t)((((t - 1) & (NSLOT - 1))) * 4 + grp) * 65536)
                    : (h1base + (size_t)(((t & (NSLOT - 1))) * 4 + grp) * 65536)) + eoff;
                __hip_atomic_store((unsigned short*)wp, hi,
                                   __ATOMIC_RELAXED, __HIP_MEMORY_SCOPE_AGENT);
                __hip_atomic_store((unsigned short*)(wp + 16), lo,
                                   __ATOMIC_RELAXED, __HIP_MEMORY_SCOPE_AGENT);
            }
        }
        asm volatile("s_waitcnt vmcnt(0)" ::: "memory");
        __syncthreads();

        // ---- barrier: tid0 publishes, wave 0 polls the group's 64 flags ----
        {
            const unsigned target = (unsigned)(t + 1);
            if (tid == 0)
                st_flag(wsB + (size_t)(grp * 64 + cu) * 16, target);
            if (w == 0) {
                const char* fb = wsB + (size_t)grp * 1024 + (size_t)lane * 16;
                for (;;) {
                    unsigned f = ld_flag(fb);
                    if (__all(f >= target)) break;
                    __builtin_amdgcn_s_sleep(2);
                }
            }
            __syncthreads();
        }
    }

    // ---- wait for ALL 256 WGs, fence, then FC ----
    if (tid < 256) {
        while (ld_flag(wsB + (size_t)tid * 16) < (unsigned)(TT + 1))
            __builtin_amdgcn_s_sleep(2);
    }
    __syncthreads();
    acquire_fence();

    // FC: block g computes out[:, 2g..2g+1]; h2(TT-1) at slot (TT-1)&31 = 31
    float* Wlds = shmem + 2176;
    ((float4*)Wlds)[tid] = ((const float4*)(Wfc + (size_t)(2 * blockIdx.x) * HH))[tid];
    __syncthreads();

    float p0 = 0.f, p1 = 0.f;
    {
        const int gr   = lane >> 4;
        const int bsub = lane & 15;
        const char* hb = h2base + (size_t)(((TT - 1) & (NSLOT - 1)) * 4 + gr) * 65536;
        #pragma unroll 4
        for (int k8 = w * 16; k8 < w * 16 + 16; ++k8) {
            const char* p = hb + (size_t)(k8 >> 2) * 2048
                          + (size_t)(bsub + ((k8 & 3) << 4)) * 32;
            bf8 hi = load_h(p);
            bf8 lo = load_h(p + 16);
            const int kb = k8 * 8;
            #pragma unroll
            for (int j = 0; j < 8; ++j) {
                float f = bf2f((unsigned short)hi[j]) + bf2f((unsigned short)lo[j]);
                p0 += f * Wlds[kb + j];
                p1 += f * Wlds[1024 + kb + j];
            }
        }
    }
    __syncthreads();
    shmem[(w * 64 + lane) * 2 + 0] = p0;
    shmem[(w * 64 + lane) * 2 + 1] = p1;
    __syncthreads();
    if (w < 2) {
        float s = bfc[2 * blockIdx.x + w];
        #pragma unroll
        for (int j = 0; j < 8; ++j) s += shmem[(j * 64 + lane) * 2 + w];
        out[(size_t)lane * OO + 2 * blockIdx.x + w] = s;
    }
}

extern "C" void kernel_launch(void* const* d_in, const int* in_sizes, int n_in,
                              void* d_out, int out_size, void* d_ws, size_t ws_size,
                              hipStream_t stream) {
    const float* x    = (const float*)d_in[0];
    const float* Wih0 = (const float*)d_in[1];
    const float* Whh0 = (const float*)d_in[2];
    const float* bih0 = (const float*)d_in[3];
    const float* bhh0 = (const float*)d_in[4];
    const float* Wih1 = (const float*)d_in[5];
    const float* Whh1 = (const float*)d_in[6];
    const float* bih1 = (const float*)d_in[7];
    const float* bhh1 = (const float*)d_in[8];
    const float* Wfc  = (const float*)d_in[9];
    const float* bfc  = (const float*)d_in[10];
    float* out = (float*)d_out;
    float* ws  = (float*)d_ws;

    // zero the flag region every call (replay-safe). ws use: 4KB + 16MB.
    hipMemsetAsync(d_ws, 0, 4096, stream);

    void* args[] = { (void*)&x,
                     (void*)&Wih0, (void*)&Whh0, (void*)&bih0, (void*)&bhh0,
                     (void*)&Wih1, (void*)&Whh1, (void*)&bih1, (void*)&bhh1,
                     (void*)&Wfc,  (void*)&bfc,  (void*)&out,  (void*)&ws };
    hipLaunchCooperativeKernel((void*)rnn_ring, dim3(256), dim3(512),
                               args, 0, stream);
}

// Round 13
// 3000.912 us; speedup vs baseline: 3.5143x; 1.3326x over previous
//
#include <hip/hip_runtime.h>
#include <cmath>

#define BB 64
#define TT 512
#define II 256
#define HH 1024
#define OO 512
#define NSLOT 32                          // h ring depth (slot = t & 31)

typedef short bf8 __attribute__((ext_vector_type(8)));    // 8 bf16 vals
typedef float f32x4 __attribute__((ext_vector_type(4)));
typedef unsigned long long u64;

#define MFMA(a, b, c) __builtin_amdgcn_mfma_f32_16x16x32_bf16((a), (b), (c), 0, 0, 0)

__device__ __forceinline__ unsigned short f2bf(float f) {
    unsigned u = __float_as_uint(f);
    return (unsigned short)((u + 0x7fffu + ((u >> 16) & 1u)) >> 16);
}
__device__ __forceinline__ float bf2f(unsigned short h) {
    return __uint_as_float((unsigned)h << 16);
}
__device__ __forceinline__ void split8(const float* v, bf8& hi, bf8& lo) {
#pragma unroll
    for (int j = 0; j < 8; ++j) {
        unsigned short h = f2bf(v[j]);
        float r = v[j] - bf2f(h);
        hi[j] = (short)h;
        lo[j] = (short)f2bf(r);
    }
}
__device__ __forceinline__ void ld8(float* v, const float* p) {
    *(float4*)v       = *(const float4*)p;
    *(float4*)(v + 4) = *(const float4*)(p + 4);
}

// Consumer h loads: PLAIN CACHED (L1+L2 merge the 64x-redundant reads) — R12.
__device__ __forceinline__ bf8 load_h(const void* p) {
    return *(const bf8*)p;
}
// Producer stores: sc1 write-through (L3-coherent) — now COALESCED 16B.
__device__ __forceinline__ void store_h16(void* p, u64 a, u64 b) {
    __hip_atomic_store((u64*)p, a, __ATOMIC_RELAXED, __HIP_MEMORY_SCOPE_AGENT);
    __hip_atomic_store((u64*)((char*)p + 8), b, __ATOMIC_RELAXED, __HIP_MEMORY_SCOPE_AGENT);
}
// Flag polls stay UNCACHED (relaxed agent atomics).
__device__ __forceinline__ unsigned ld_flag(const void* p) {
    return __hip_atomic_load((const unsigned*)p, __ATOMIC_RELAXED, __HIP_MEMORY_SCOPE_AGENT);
}
__device__ __forceinline__ void st_flag(void* p, unsigned v) {
    __hip_atomic_store((unsigned*)p, v, __ATOMIC_RELAXED, __HIP_MEMORY_SCOPE_AGENT);
}
__device__ __forceinline__ void acquire_fence() {
    __builtin_amdgcn_fence(__ATOMIC_ACQUIRE, "agent");
    asm volatile("" ::: "memory");
}

// h layout per (layer, slot, group) 64KB: 32 K-chunks x 64 lanes x (16B hi+16B lo).
// h[b][k]: chunk k>>5, lane (b&15)+16*((k&31)>>3), j=k&7: hi j*2, lo j*2+16.
// R12 structure: grp=bid&3 (16 batches), cu=bid>>2 (rows cu*16..+15, both layers).
// Waves 0-3: L0; waves 4-7: L1. Interval t: h1(t), h2(t-1). Ring depth 32,
// acquire fence every 16 intervals (staleness proof: R12 notes; skew<=1).
__global__ __launch_bounds__(512, 1) void rnn_ring2(
    const float* __restrict__ x,
    const float* __restrict__ Wih0, const float* __restrict__ Whh0,
    const float* __restrict__ bih0, const float* __restrict__ bhh0,
    const float* __restrict__ Wih1, const float* __restrict__ Whh1,
    const float* __restrict__ bih1, const float* __restrict__ bhh1,
    const float* __restrict__ Wfc,  const float* __restrict__ bfc,
    float* __restrict__ out, float* __restrict__ ws)
{
    const int tid  = threadIdx.x;
    const int w    = tid >> 6;      // wave 0..7
    const int lane = tid & 63;
    const int col  = lane & 15;
    const int kg   = lane >> 4;
    const int grp  = blockIdx.x & 3;
    const int cu   = blockIdx.x >> 2;
    const int rb   = cu * 16;
    const int b0   = grp * 16;

    __shared__ float shmem[4224];   // Ps [8][16][17]=2176 | staging 512 fl (2KB) | FC reuse
    char* staging = (char*)(shmem + 2176);

    char* wsB = (char*)ws;
    // flags: [grp*64+cu]*16B, 4KB total
    char* h1base = wsB + 4096;                              // [32 slot][4 grp] 64KB = 8MB
    char* h2base = h1base + (size_t)NSLOT * 4 * 65536;      // [32 slot][4 grp] 64KB = 8MB

    // ---- preload weight B-fragments into registers (once) — identical R12 ----
    bf8 wreg[32];
    if (w < 4) {
        #pragma unroll
        for (int c = 0; c < 2; ++c) {
            const float* p = Wih0 + (size_t)(rb + col) * II + (w * 64 + c * 32 + kg * 8);
            float v[8];
            ld8(v, p);
            split8(v, wreg[2 * c], wreg[2 * c + 1]);
        }
        #pragma unroll
        for (int c = 0; c < 8; ++c) {
            const float* p = Whh0 + (size_t)(rb + col) * HH + (w * 256 + c * 32 + kg * 8);
            float v[8];
            ld8(v, p);
            split8(v, wreg[4 + 2 * c], wreg[5 + 2 * c]);
        }
    } else {
        const int w4 = w - 4;
        #pragma unroll
        for (int c = 0; c < 8; ++c) {
            const float* p = Wih1 + (size_t)(rb + col) * HH + (w4 * 256 + c * 32 + kg * 8);
            float v[8];
            ld8(v, p);
            split8(v, wreg[2 * c], wreg[2 * c + 1]);
        }
        #pragma unroll
        for (int c = 0; c < 8; ++c) {
            const float* p = Whh1 + (size_t)(rb + col) * HH + (w4 * 256 + c * 32 + kg * 8);
            float v[8];
            ld8(v, p);
            split8(v, wreg[16 + 2 * c], wreg[17 + 2 * c]);
        }
    }

    // ---- epilogue role constants ----
    const int side = tid >> 8;        // 0: L0 tile, 1: L1 tile
    const int u    = tid & 255;
    const int eb   = u & 15;          // batch sub
    const int ekk  = u >> 4;          // row sub
    const float bsum = (side == 0) ? (bih0[rb + ekk] + bhh0[rb + ekk])
                                   : (bih1[rb + ekk] + bhh1[rb + ekk]);
    // staging slot for this thread's output value (hi at +0, lo at +16)
    const int stg = side * 1024 + (eb + 16 * (ekk >> 3)) * 32 + (ekk & 7) * 2;
    // coalesced-store role (threads 0..127): 16B unit u6 of side st_s
    const int st_s  = tid >> 6;       // valid when tid<128: 0 or 1
    const int u6    = tid & 63;
    const size_t st_dst_off = (size_t)(cu >> 1) * 2048
                            + (size_t)(32 * (cu & 1) + (u6 >> 1)) * 32 + (u6 & 1) * 16;
    const int st_src_off = st_s * 1024 + (u6 >> 1) * 32 + (u6 & 1) * 16;

    acquire_fence();   // kill stale lines from a previous graph replay

    // x double-buffer prefetch (step 0)
    float xva[8], xvb[8];
    if (w < 4) {
        const float* xb = x + (size_t)(b0 + col) * TT * II + (w * 64 + kg * 8);
        ld8(xva, xb); ld8(xvb, xb + 32);
    }

    for (int t = 0; t <= TT; ++t) {
        // periodic invalidate (R12 staleness proof: ring 32, fences every 16, skew<=1)
        if ((t & 15) == 0) acquire_fence();

        f32x4 acc0 = {0.f, 0.f, 0.f, 0.f};
        f32x4 acc1 = {0.f, 0.f, 0.f, 0.f};

        const char* h1r = h1base + (size_t)(((t - 1) & (NSLOT - 1)) * 4 + grp) * 65536;
        const char* h2r = h2base + (size_t)(((t - 2) & (NSLOT - 1)) * 4 + grp) * 65536;

        if (w < 4) {
            if (t < TT) {
                bf8 ahi, alo;
                split8(xva, ahi, alo);
                acc0 = MFMA(ahi, wreg[0], acc0);
                acc0 = MFMA(ahi, wreg[1], acc0);
                acc0 = MFMA(alo, wreg[0], acc0);
                split8(xvb, ahi, alo);
                acc1 = MFMA(ahi, wreg[2], acc1);
                acc1 = MFMA(ahi, wreg[3], acc1);
                acc1 = MFMA(alo, wreg[2], acc1);
                if (t > 0) {
                    const char* hb = h1r + (size_t)(w * 8) * 2048 + lane * 32;
                    #pragma unroll
                    for (int c = 0; c < 8; ++c) {
                        bf8 hhi = load_h(hb + c * 2048);
                        bf8 hlo = load_h(hb + c * 2048 + 16);
                        if (c & 1) {
                            acc1 = MFMA(hhi, wreg[4 + 2 * c], acc1);
                            acc1 = MFMA(hhi, wreg[5 + 2 * c], acc1);
                            acc1 = MFMA(hlo, wreg[4 + 2 * c], acc1);
                        } else {
                            acc0 = MFMA(hhi, wreg[4 + 2 * c], acc0);
                            acc0 = MFMA(hhi, wreg[5 + 2 * c], acc0);
                            acc0 = MFMA(hlo, wreg[4 + 2 * c], acc0);
                        }
                    }
                }
            }
        } else {
            if (t >= 1) {
                const int w4 = w - 4;
                const char* hb = h1r + (size_t)(w4 * 8) * 2048 + lane * 32;
                #pragma unroll
                for (int c = 0; c < 8; ++c) {
                    bf8 hhi = load_h(hb + c * 2048);
                    bf8 hlo = load_h(hb + c * 2048 + 16);
                    if (c & 1) {
                        acc1 = MFMA(hhi, wreg[2 * c], acc1);
                        acc1 = MFMA(hhi, wreg[2 * c + 1], acc1);
                        acc1 = MFMA(hlo, wreg[2 * c], acc1);
                    } else {
                        acc0 = MFMA(hhi, wreg[2 * c], acc0);
                        acc0 = MFMA(hhi, wreg[2 * c + 1], acc0);
                        acc0 = MFMA(hlo, wreg[2 * c], acc0);
                    }
                }
                if (t >= 2) {
                    const char* hb2 = h2r + (size_t)(w4 * 8) * 2048 + lane * 32;
                    #pragma unroll
                    for (int c = 0; c < 8; ++c) {
                        bf8 hhi = load_h(hb2 + c * 2048);
                        bf8 hlo = load_h(hb2 + c * 2048 + 16);
                        if (c & 1) {
                            acc1 = MFMA(hhi, wreg[16 + 2 * c], acc1);
                            acc1 = MFMA(hhi, wreg[17 + 2 * c], acc1);
                            acc1 = MFMA(hlo, wreg[16 + 2 * c], acc1);
                        } else {
                            acc0 = MFMA(hhi, wreg[16 + 2 * c], acc0);
                            acc0 = MFMA(hhi, wreg[17 + 2 * c], acc0);
                            acc0 = MFMA(hlo, wreg[16 + 2 * c], acc0);
                        }
                    }
                }
            }
        }

        // ---- write partial tiles ----
        {
            f32x4 s4 = acc0 + acc1;
            #pragma unroll
            for (int r = 0; r < 4; ++r)
                shmem[(w * 16 + kg * 4 + r) * 17 + col] = s4[r];
        }
        __syncthreads();

        // ---- reduce, bias, tanh, split -> LDS staging (2KB) ----
        {
            const bool doit = (side == 0) ? (t < TT) : (t >= 1);
            if (doit) {
                const int wb = side * 4;
                float s = shmem[((wb + 0) * 16 + eb) * 17 + ekk]
                        + shmem[((wb + 1) * 16 + eb) * 17 + ekk]
                        + shmem[((wb + 2) * 16 + eb) * 17 + ekk]
                        + shmem[((wb + 3) * 16 + eb) * 17 + ekk];
                s += bsum;
                const float val = tanhf(s);
                const unsigned short hi = f2bf(val);
                const unsigned short lo = f2bf(val - bf2f(hi));
                *(unsigned short*)(staging + stg)      = hi;
                *(unsigned short*)(staging + stg + 16) = lo;
            }
        }
        __syncthreads();

        // ---- coalesced sc1 store: 128 threads x 16B (full-line far writes) ----
        if (tid < 128) {
            const bool doit = st_s ? (t >= 1) : (t < TT);
            if (doit) {
                char* hw = st_s
                    ? (h2base + (size_t)((((t - 1) & (NSLOT - 1))) * 4 + grp) * 65536)
                    : (h1base + (size_t)(((t & (NSLOT - 1))) * 4 + grp) * 65536);
                const char* src = staging + st_src_off;
                store_h16(hw + st_dst_off, *(const u64*)src, *(const u64*)(src + 8));
            }
        }
        asm volatile("s_waitcnt vmcnt(0)" ::: "memory");
        __syncthreads();

        if (tid == 0)
            st_flag(wsB + (size_t)(grp * 64 + cu) * 16, (unsigned)(t + 1));

        // ---- x prefetch for step t+1 BEFORE the poll (hides under the spin) ----
        if (w < 4 && t + 1 < TT) {
            const float* xb = x + ((size_t)(b0 + col) * TT + (t + 1)) * II + (w * 64 + kg * 8);
            ld8(xva, xb); ld8(xvb, xb + 32);
        }

        // ---- barrier: wave 0 polls the group's 64 flags ----
        {
            const unsigned target = (unsigned)(t + 1);
            if (w == 0) {
                const char* fb = wsB + (size_t)grp * 1024 + (size_t)lane * 16;
                for (;;) {
                    unsigned f = ld_flag(fb);
                    if (__all(f >= target)) break;
                    __builtin_amdgcn_s_sleep(2);
                }
            }
            __syncthreads();
        }
    }

    // ---- wait for ALL 256 WGs, fence, then FC ----
    if (tid < 256) {
        while (ld_flag(wsB + (size_t)tid * 16) < (unsigned)(TT + 1))
            __builtin_amdgcn_s_sleep(2);
    }
    __syncthreads();
    acquire_fence();

    // FC: block g computes out[:, 2g..2g+1]; h2(TT-1) at slot 31
    float* Wlds = shmem + 2176;
    ((float4*)Wlds)[tid] = ((const float4*)(Wfc + (size_t)(2 * blockIdx.x) * HH))[tid];
    __syncthreads();

    float p0 = 0.f, p1 = 0.f;
    {
        const int gr   = lane >> 4;
        const int bsub = lane & 15;
        const char* hb = h2base + (size_t)(((TT - 1) & (NSLOT - 1)) * 4 + gr) * 65536;
        #pragma unroll 4
        for (int k8 = w * 16; k8 < w * 16 + 16; ++k8) {
            const char* p = hb + (size_t)(k8 >> 2) * 2048
                          + (size_t)(bsub + ((k8 & 3) << 4)) * 32;
            bf8 hi = load_h(p);
            bf8 lo = load_h(p + 16);
            const int kb = k8 * 8;
            #pragma unroll
            for (int j = 0; j < 8; ++j) {
                float f = bf2f((unsigned short)hi[j]) + bf2f((unsigned short)lo[j]);
                p0 += f * Wlds[kb + j];
                p1 += f * Wlds[1024 + kb + j];
            }
        }
    }
    __syncthreads();
    shmem[(w * 64 + lane) * 2 + 0] = p0;
    shmem[(w * 64 + lane) * 2 + 1] = p1;
    __syncthreads();
    if (w < 2) {
        float s = bfc[2 * blockIdx.x + w];
        #pragma unroll
        for (int j = 0; j < 8; ++j) s += shmem[(j * 64 + lane) * 2 + w];
        out[(size_t)lane * OO + 2 * blockIdx.x + w] = s;
    }
}

extern "C" void kernel_launch(void* const* d_in, const int* in_sizes, int n_in,
                              void* d_out, int out_size, void* d_ws, size_t ws_size,
                              hipStream_t stream) {
    const float* x    = (const float*)d_in[0];
    const float* Wih0 = (const float*)d_in[1];
    const float* Whh0 = (const float*)d_in[2];
    const float* bih0 = (const float*)d_in[3];
    const float* bhh0 = (const float*)d_in[4];
    const float* Wih1 = (const float*)d_in[5];
    const float* Whh1 = (const float*)d_in[6];
    const float* bih1 = (const float*)d_in[7];
    const float* bhh1 = (const float*)d_in[8];
    const float* Wfc  = (const float*)d_in[9];
    const float* bfc  = (const float*)d_in[10];
    float* out = (float*)d_out;
    float* ws  = (float*)d_ws;

    // zero the flag region every call (replay-safe). ws use: 4KB + 16MB.
    hipMemsetAsync(d_ws, 0, 4096, stream);

    void* args[] = { (void*)&x,
                     (void*)&Wih0, (void*)&Whh0, (void*)&bih0, (void*)&bhh0,
                     (void*)&Wih1, (void*)&Whh1, (void*)&bih1, (void*)&bhh1,
                     (void*)&Wfc,  (void*)&bfc,  (void*)&out,  (void*)&ws };
    hipLaunchCooperativeKernel((void*)rnn_ring2, dim3(256), dim3(512),
                               args, 0, stream);
}

// Round 14
// 2841.121 us; speedup vs baseline: 3.7119x; 1.0562x over previous
//
#include <hip/hip_runtime.h>
#include <cmath>

#define BB 64
#define TT 512
#define II 256
#define HH 1024
#define OO 512
#define NSLOT 32
#define LAG 24

typedef short bf8 __attribute__((ext_vector_type(8)));
typedef float f32x4 __attribute__((ext_vector_type(4)));
typedef unsigned long long u64;

#define MFMA(a, b, c) __builtin_amdgcn_mfma_f32_16x16x32_bf16((a), (b), (c), 0, 0, 0)

__device__ __forceinline__ unsigned short f2bf(float f) {
    unsigned u = __float_as_uint(f);
    return (unsigned short)((u + 0x7fffu + ((u >> 16) & 1u)) >> 16);
}
__device__ __forceinline__ float bf2f(unsigned short h) {
    return __uint_as_float((unsigned)h << 16);
}
__device__ __forceinline__ void split8(const float* v, bf8& hi, bf8& lo) {
#pragma unroll
    for (int j = 0; j < 8; ++j) {
        unsigned short h = f2bf(v[j]);
        float r = v[j] - bf2f(h);
        hi[j] = (short)h;
        lo[j] = (short)f2bf(r);
    }
}
__device__ __forceinline__ void ld8(float* v, const float* p) {
    *(float4*)v       = *(const float4*)p;
    *(float4*)(v + 4) = *(const float4*)(p + 4);
}
// Consumer h loads: plain cached (L2 merges redundant reads) — R12/R13 proven.
__device__ __forceinline__ bf8 load_h(const void* p) { return *(const bf8*)p; }
// Producer stores: sc1 write-through, coalesced 16B — R13 proven.
__device__ __forceinline__ void store_h16(void* p, u64 a, u64 b) {
    __hip_atomic_store((u64*)p, a, __ATOMIC_RELAXED, __HIP_MEMORY_SCOPE_AGENT);
    __hip_atomic_store((u64*)((char*)p + 8), b, __ATOMIC_RELAXED, __HIP_MEMORY_SCOPE_AGENT);
}
__device__ __forceinline__ unsigned ld_flag(const void* p) {
    return __hip_atomic_load((const unsigned*)p, __ATOMIC_RELAXED, __HIP_MEMORY_SCOPE_AGENT);
}
__device__ __forceinline__ void st_flag(void* p, unsigned v) {
    __hip_atomic_store((unsigned*)p, v, __ATOMIC_RELAXED, __HIP_MEMORY_SCOPE_AGENT);
}
__device__ __forceinline__ void acquire_fence() {
    __builtin_amdgcn_fence(__ATOMIC_ACQUIRE, "agent");
    asm volatile("" ::: "memory");
}

// h layout per (layer, slot, group) 64KB: 32 K-chunks x 64 lanes x (16B hi+16B lo).
// h[b][k]: chunk k>>5, lane (b&15)+16*((k&31)>>3), j=k&7: hi j*2, lo j*2+16.
//
// Grid 256 x 512: grp=bid&3 (16 batches), layer=(bid>>2)&1, slot=bid>>3 ->
// rows slot*32..+31 of its layer (2 mfma tiles). 8 waves K-split.
// L0-WG step t: h1(t) = tanh(x(t)@Wih0^T + b + h1(t-1)@Whh0^T); fA[slot]=t+1.
//   Waits: fA>=t (h1(t-1) from all 32 L0 peers), fB>=t-LAG (ring backpressure).
// L1-WG step t: h2(t) = tanh(h1(t)@Wih1^T + b + h2(t-1)@Whh1^T); fB[slot]=t+1.
//   Waits: fB>=t (h2(t-1) peers), fA>=t+1 (h1(t), slack since L0 runs ahead).
// Deadlock-free (blocked pair needs s<t-LAG and t<s+1: contradiction).
// Cached-read staleness: each reader re-reads an address every 32 OWN steps
// with >=2 OWN fences (every 16) in between; drift bounded by LAG<32-2.
__global__ __launch_bounds__(512, 1) void rnn_lag(
    const float* __restrict__ x,
    const float* __restrict__ Wih0, const float* __restrict__ Whh0,
    const float* __restrict__ bih0, const float* __restrict__ bhh0,
    const float* __restrict__ Wih1, const float* __restrict__ Whh1,
    const float* __restrict__ bih1, const float* __restrict__ bhh1,
    const float* __restrict__ Wfc,  const float* __restrict__ bfc,
    float* __restrict__ out, float* __restrict__ ws)
{
    __shared__ float shmem[4864];      // Ps [8][2][16][17]=4352 | staging 512 fl
    char* staging = (char*)(shmem + 4352);

    const int tid  = threadIdx.x;
    const int w    = tid >> 6;
    const int lane = tid & 63;
    const int col  = lane & 15;
    const int kg   = lane >> 4;
    const int bid  = blockIdx.x;
    const int grp   = bid & 3;
    const int layer = (bid >> 2) & 1;
    const int slot  = bid >> 3;        // 0..31
    const int rb    = slot * 32;
    const int b0    = grp * 16;

    char* wsB    = (char*)ws;
    char* fA     = wsB;                // 128 x 16B (L0 flags)
    char* fB     = wsB + 2048;         // 128 x 16B (L1 flags)
    char* h1base = wsB + 4096;         // [32 slot][4 grp] 64KB = 8MB
    char* h2base = h1base + (size_t)NSLOT * 4 * 65536;   // 8MB

    // ---- weight preload (VGPR). L0: [n][0..3]=Whh0 chunks, [n][4]=Wih0 chunk w.
    //                              L1: [n][0..3]=Wih1, [n][4..7]=Whh1.
    bf8 wh[2][8], wl[2][8];
    {
        float v[8];
        if (layer == 0) {
            #pragma unroll
            for (int n = 0; n < 2; ++n) {
                ld8(v, Wih0 + (size_t)(rb + n * 16 + col) * II + (w * 32 + kg * 8));
                split8(v, wh[n][4], wl[n][4]);
                #pragma unroll
                for (int c = 0; c < 4; ++c) {
                    ld8(v, Whh0 + (size_t)(rb + n * 16 + col) * HH + ((w * 4 + c) * 32 + kg * 8));
                    split8(v, wh[n][c], wl[n][c]);
                }
            }
        } else {
            #pragma unroll
            for (int n = 0; n < 2; ++n)
                #pragma unroll
                for (int c = 0; c < 4; ++c) {
                    ld8(v, Wih1 + (size_t)(rb + n * 16 + col) * HH + ((w * 4 + c) * 32 + kg * 8));
                    split8(v, wh[n][c], wl[n][c]);
                    ld8(v, Whh1 + (size_t)(rb + n * 16 + col) * HH + ((w * 4 + c) * 32 + kg * 8));
                    split8(v, wh[n][4 + c], wl[n][4 + c]);
                }
        }
    }

    // ---- epilogue role: one thread per output element (2 tiles x 16 x 16) ----
    const int n_  = tid >> 8;
    const int ekk = (tid >> 4) & 15;
    const int eb  = tid & 15;
    const int R   = rb + n_ * 16 + ekk;
    const float bsum = layer ? (bih1[R] + bhh1[R]) : (bih0[R] + bhh0[R]);
    const int kk5 = n_ * 16 + ekk;
    const int stg = (eb + 16 * (kk5 >> 3)) * 32 + (kk5 & 7) * 2;

    acquire_fence();   // kill stale lines from a previous graph replay

    float xv[8];
    if (layer == 0)
        ld8(xv, x + (size_t)(b0 + col) * TT * II + (w * 32 + kg * 8));

    for (int t = 0; t < TT; ++t) {
        if ((t & 15) == 0) acquire_fence();

        f32x4 acc0 = {0.f, 0.f, 0.f, 0.f};
        f32x4 acc1 = {0.f, 0.f, 0.f, 0.f};

        // x-part MFMAs before the poll (no dependency on flags)
        if (layer == 0) {
            bf8 xh, xl;
            split8(xv, xh, xl);
            acc0 = MFMA(xh, wh[0][4], acc0); acc0 = MFMA(xh, wl[0][4], acc0);
            acc0 = MFMA(xl, wh[0][4], acc0);
            acc1 = MFMA(xh, wh[1][4], acc1); acc1 = MFMA(xh, wl[1][4], acc1);
            acc1 = MFMA(xl, wh[1][4], acc1);
        }

        // ---- poll (wave 0): 32 peer flags + 32 cross-layer slack flags ----
        if (w == 0) {
            const char* fp;
            int tgt;
            if (layer == 0) {
                fp  = (lane < 32 ? fA : fB) + (size_t)(grp * 32 + (lane & 31)) * 16;
                tgt = (lane < 32) ? t : (t - LAG);
            } else {
                fp  = (lane < 32 ? fB : fA) + (size_t)(grp * 32 + (lane & 31)) * 16;
                tgt = (lane < 32) ? t : (t + 1);
            }
            for (;;) {
                int f = (int)ld_flag(fp);
                if (__all(f >= tgt)) break;
                __builtin_amdgcn_s_sleep(1);
            }
        }
        __syncthreads();

        // ---- h MFMAs ----
        if (layer == 0) {
            if (t >= 1) {
                const char* h1r = h1base + (size_t)(((t - 1) & 31) * 4 + grp) * 65536;
                #pragma unroll
                for (int c = 0; c < 4; ++c) {
                    const char* p = h1r + (size_t)(w * 4 + c) * 2048 + lane * 32;
                    bf8 hh = load_h(p), hl = load_h(p + 16);
                    acc0 = MFMA(hh, wh[0][c], acc0); acc0 = MFMA(hh, wl[0][c], acc0);
                    acc0 = MFMA(hl, wh[0][c], acc0);
                    acc1 = MFMA(hh, wh[1][c], acc1); acc1 = MFMA(hh, wl[1][c], acc1);
                    acc1 = MFMA(hl, wh[1][c], acc1);
                }
            }
        } else {
            {
                const char* h1r = h1base + (size_t)((t & 31) * 4 + grp) * 65536;
                #pragma unroll
                for (int c = 0; c < 4; ++c) {
                    const char* p = h1r + (size_t)(w * 4 + c) * 2048 + lane * 32;
                    bf8 hh = load_h(p), hl = load_h(p + 16);
                    acc0 = MFMA(hh, wh[0][c], acc0); acc0 = MFMA(hh, wl[0][c], acc0);
                    acc0 = MFMA(hl, wh[0][c], acc0);
                    acc1 = MFMA(hh, wh[1][c], acc1); acc1 = MFMA(hh, wl[1][c], acc1);
                    acc1 = MFMA(hl, wh[1][c], acc1);
                }
            }
            if (t >= 1) {
                const char* h2r = h2base + (size_t)(((t - 1) & 31) * 4 + grp) * 65536;
                #pragma unroll
                for (int c = 0; c < 4; ++c) {
                    const char* p = h2r + (size_t)(w * 4 + c) * 2048 + lane * 32;
                    bf8 hh = load_h(p), hl = load_h(p + 16);
                    acc0 = MFMA(hh, wh[0][4 + c], acc0); acc0 = MFMA(hh, wl[0][4 + c], acc0);
                    acc0 = MFMA(hl, wh[0][4 + c], acc0);
                    acc1 = MFMA(hh, wh[1][4 + c], acc1); acc1 = MFMA(hh, wl[1][4 + c], acc1);
                    acc1 = MFMA(hl, wh[1][4 + c], acc1);
                }
            }
        }

        // ---- partials: Ps[(w,n)][row=batch][col=wrow] (convention verified R5+) ----
        #pragma unroll
        for (int r = 0; r < 4; ++r) {
            shmem[(w * 2 + 0) * 272 + (kg * 4 + r) * 17 + col] = acc0[r];
            shmem[(w * 2 + 1) * 272 + (kg * 4 + r) * 17 + col] = acc1[r];
        }
        __syncthreads();

        // ---- reduce over 8 waves + bias + tanh + split -> staging ----
        {
            float s = bsum;
            #pragma unroll
            for (int wv = 0; wv < 8; ++wv)
                s += shmem[(wv * 2 + n_) * 272 + eb * 17 + ekk];
            const float val = tanhf(s);
            const unsigned short hi = f2bf(val);
            const unsigned short lo = f2bf(val - bf2f(hi));
            *(unsigned short*)(staging + stg)      = hi;
            *(unsigned short*)(staging + stg + 16) = lo;
        }
        __syncthreads();

        // ---- coalesced 2KB chunk store (128 x 16B, sc1) ----
        {
            char* hw = (layer ? h2base : h1base)
                     + (size_t)((t & 31) * 4 + grp) * 65536 + (size_t)slot * 2048;
            if (tid < 128) {
                const char* src = staging + tid * 16;
                store_h16(hw + tid * 16, *(const u64*)src, *(const u64*)(src + 8));
            }
        }
        asm volatile("s_waitcnt vmcnt(0)" ::: "memory");
        __syncthreads();
        if (tid == 0)
            st_flag((layer ? fB : fA) + (size_t)(grp * 32 + slot) * 16, (unsigned)(t + 1));

        // ---- x prefetch for t+1 (hides under next poll) ----
        if (layer == 0 && t + 1 < TT)
            ld8(xv, x + ((size_t)(b0 + col) * TT + (t + 1)) * II + (w * 32 + kg * 8));
    }

    // ---- FC gate: all 128 L1 flags >= TT, fence, then FC ----
    if (tid < 128) {
        while ((int)ld_flag(fB + (size_t)tid * 16) < TT)
            __builtin_amdgcn_s_sleep(2);
    }
    __syncthreads();
    acquire_fence();

    // FC: block computes out[:, 2*bid .. 2*bid+1]; h2(TT-1) at slot 31
    float* Wlds = shmem + 2304;
    ((float4*)Wlds)[tid] = ((const float4*)(Wfc + (size_t)(2 * bid) * HH))[tid];
    __syncthreads();

    float p0 = 0.f, p1 = 0.f;
    {
        const int gr   = lane >> 4;
        const int bsub = lane & 15;
        const char* hb = h2base + (size_t)(((TT - 1) & 31) * 4 + gr) * 65536;
        #pragma unroll 4
        for (int k8 = w * 16; k8 < w * 16 + 16; ++k8) {
            const char* p = hb + (size_t)(k8 >> 2) * 2048
                          + (size_t)(bsub + ((k8 & 3) << 4)) * 32;
            bf8 hi = load_h(p), lo = load_h(p + 16);
            const int kb = k8 * 8;
            #pragma unroll
            for (int j = 0; j < 8; ++j) {
                float f = bf2f((unsigned short)hi[j]) + bf2f((unsigned short)lo[j]);
                p0 += f * Wlds[kb + j];
                p1 += f * Wlds[1024 + kb + j];
            }
        }
    }
    __syncthreads();
    shmem[(w * 64 + lane) * 2 + 0] = p0;
    shmem[(w * 64 + lane) * 2 + 1] = p1;
    __syncthreads();
    if (w < 2) {
        float s = bfc[2 * bid + w];
        #pragma unroll
        for (int j = 0; j < 8; ++j) s += shmem[(j * 64 + lane) * 2 + w];
        out[(size_t)lane * OO + 2 * bid + w] = s;
    }
}

extern "C" void kernel_launch(void* const* d_in, const int* in_sizes, int n_in,
                              void* d_out, int out_size, void* d_ws, size_t ws_size,
                              hipStream_t stream) {
    const float* x    = (const float*)d_in[0];
    const float* Wih0 = (const float*)d_in[1];
    const float* Whh0 = (const float*)d_in[2];
    const float* bih0 = (const float*)d_in[3];
    const float* bhh0 = (const float*)d_in[4];
    const float* Wih1 = (const float*)d_in[5];
    const float* Whh1 = (const float*)d_in[6];
    const float* bih1 = (const float*)d_in[7];
    const float* bhh1 = (const float*)d_in[8];
    const float* Wfc  = (const float*)d_in[9];
    const float* bfc  = (const float*)d_in[10];
    float* out = (float*)d_out;
    float* ws  = (float*)d_ws;

    // zero both flag arrays every call (replay-safe). ws use: 4KB + 16MB.
    hipMemsetAsync(d_ws, 0, 4096, stream);

    void* args[] = { (void*)&x,
                     (void*)&Wih0, (void*)&Whh0, (void*)&bih0, (void*)&bhh0,
                     (void*)&Wih1, (void*)&Whh1, (void*)&bih1, (void*)&bhh1,
                     (void*)&Wfc,  (void*)&bfc,  (void*)&out,  (void*)&ws };
    hipLaunchCooperativeKernel((void*)rnn_lag, dim3(256), dim3(512),
                               args, 0, stream);
}

// Round 15
// 2414.304 us; speedup vs baseline: 4.3682x; 1.1768x over previous
//
#include <hip/hip_runtime.h>
#include <cmath>

#define BB 64
#define TT 512
#define II 256
#define HH 1024
#define OO 512
#define LAG 24

typedef short bf8 __attribute__((ext_vector_type(8)));
typedef float f32x4 __attribute__((ext_vector_type(4)));
typedef unsigned long long u64;

#define MFMA(a, b, c) __builtin_amdgcn_mfma_f32_16x16x32_bf16((a), (b), (c), 0, 0, 0)

__device__ __forceinline__ unsigned short f2bf(float f) {
    unsigned u = __float_as_uint(f);
    return (unsigned short)((u + 0x7fffu + ((u >> 16) & 1u)) >> 16);
}
__device__ __forceinline__ float bf2f(unsigned short h) {
    return __uint_as_float((unsigned)h << 16);
}
__device__ __forceinline__ void split8(const float* v, bf8& hi, bf8& lo) {
#pragma unroll
    for (int j = 0; j < 8; ++j) {
        unsigned short h = f2bf(v[j]);
        float r = v[j] - bf2f(h);
        hi[j] = (short)h;
        lo[j] = (short)f2bf(r);
    }
}
__device__ __forceinline__ void ld8(float* v, const float* p) {
    *(float4*)v       = *(const float4*)p;
    *(float4*)(v + 4) = *(const float4*)(p + 4);
}
// Consumer h loads: plain cached (L2 merges redundant reads) — R12/R13 proven.
__device__ __forceinline__ bf8 load_h(const void* p) { return *(const bf8*)p; }
// Producer stores: sc1 write-through, coalesced 16B — R13 proven.
__device__ __forceinline__ void store_h16(void* p, u64 a, u64 b) {
    __hip_atomic_store((u64*)p, a, __ATOMIC_RELAXED, __HIP_MEMORY_SCOPE_AGENT);
    __hip_atomic_store((u64*)((char*)p + 8), b, __ATOMIC_RELAXED, __HIP_MEMORY_SCOPE_AGENT);
}
__device__ __forceinline__ unsigned ld_flag(const void* p) {
    return __hip_atomic_load((const unsigned*)p, __ATOMIC_RELAXED, __HIP_MEMORY_SCOPE_AGENT);
}
__device__ __forceinline__ void st_flag(void* p, unsigned v) {
    __hip_atomic_store((unsigned*)p, v, __ATOMIC_RELAXED, __HIP_MEMORY_SCOPE_AGENT);
}
__device__ __forceinline__ void acquire_fence() {
    __builtin_amdgcn_fence(__ATOMIC_ACQUIRE, "agent");
    asm volatile("" ::: "memory");
}

// h layout per (layer, slot, group) 64KB: 32 K-chunks x 64 lanes x (16B hi+16B lo).
// h[b][k]: chunk k>>5, lane (b&15)+16*((k&31)>>3), j=k&7: hi j*2, lo j*2+16.
//
// R14 structure; ring depth & fence period now runtime (sm = depth-1, fpm =
// period-1), chosen from ws_size. Staleness: a consumer re-reads an address
// only after depth own-steps with >=2 own fences in between (period = depth/2).
// L0-WG step t: h1(t); waits fA>=t (peers), fB>=t-LAG (backpressure; LAG<depth-2).
// L1-WG step t: h2(t); waits fB>=t (peers), fA>=t+1 (h1(t), slack).
// Deadlock-free: blocked pair needs s<t-LAG and t<s+1 — contradiction.
__global__ __launch_bounds__(512, 1) void rnn_lag2(
    const float* __restrict__ x,
    const float* __restrict__ Wih0, const float* __restrict__ Whh0,
    const float* __restrict__ bih0, const float* __restrict__ bhh0,
    const float* __restrict__ Wih1, const float* __restrict__ Whh1,
    const float* __restrict__ bih1, const float* __restrict__ bhh1,
    const float* __restrict__ Wfc,  const float* __restrict__ bfc,
    float* __restrict__ out, float* __restrict__ ws,
    int sm, int fpm)
{
    // partials [8 waves][2 tiles][16][18] = 4608 fl (stride 18: 2-way banks, free)
    // staging at +4608 (512 fl). FC reuses [2560,4608) for Wfc rows.
    __shared__ float shmem[5120];
    char* staging = (char*)(shmem + 4608);

    const int tid  = threadIdx.x;
    const int w    = tid >> 6;
    const int lane = tid & 63;
    const int col  = lane & 15;
    const int kg   = lane >> 4;
    const int bid  = blockIdx.x;
    const int grp   = bid & 3;
    const int layer = (bid >> 2) & 1;
    const int slot  = bid >> 3;        // 0..31
    const int rb    = slot * 32;
    const int b0    = grp * 16;

    char* wsB    = (char*)ws;
    char* fA     = wsB;                // 128 x 16B (L0 flags)
    char* fB     = wsB + 2048;         // 128 x 16B (L1 flags)
    char* h1base = wsB + 4096;         // [depth slot][4 grp] 64KB
    char* h2base = h1base + (size_t)(sm + 1) * 4 * 65536;

    // ---- weight preload (VGPR) — identical R14 ----
    bf8 wh[2][8], wl[2][8];
    {
        float v[8];
        if (layer == 0) {
            #pragma unroll
            for (int n = 0; n < 2; ++n) {
                ld8(v, Wih0 + (size_t)(rb + n * 16 + col) * II + (w * 32 + kg * 8));
                split8(v, wh[n][4], wl[n][4]);
                #pragma unroll
                for (int c = 0; c < 4; ++c) {
                    ld8(v, Whh0 + (size_t)(rb + n * 16 + col) * HH + ((w * 4 + c) * 32 + kg * 8));
                    split8(v, wh[n][c], wl[n][c]);
                }
            }
        } else {
            #pragma unroll
            for (int n = 0; n < 2; ++n)
                #pragma unroll
                for (int c = 0; c < 4; ++c) {
                    ld8(v, Wih1 + (size_t)(rb + n * 16 + col) * HH + ((w * 4 + c) * 32 + kg * 8));
                    split8(v, wh[n][c], wl[n][c]);
                    ld8(v, Whh1 + (size_t)(rb + n * 16 + col) * HH + ((w * 4 + c) * 32 + kg * 8));
                    split8(v, wh[n][4 + c], wl[n][4 + c]);
                }
        }
    }

    // ---- epilogue role: one thread per output element (2 tiles x 16 x 16) ----
    const int n_  = tid >> 8;
    const int ekk = (tid >> 4) & 15;
    const int eb  = tid & 15;
    const int R   = rb + n_ * 16 + ekk;
    const float bsum = layer ? (bih1[R] + bhh1[R]) : (bih0[R] + bhh0[R]);
    const int kk5 = n_ * 16 + ekk;
    const int stg = (eb + 16 * (kk5 >> 3)) * 32 + (kk5 & 7) * 2;

    acquire_fence();   // kill stale lines from a previous graph replay

    float xv[8];
    if (layer == 0)
        ld8(xv, x + (size_t)(b0 + col) * TT * II + (w * 32 + kg * 8));

    for (int t = 0; t < TT; ++t) {
        if ((t & fpm) == 0) acquire_fence();

        f32x4 acc0 = {0.f, 0.f, 0.f, 0.f};
        f32x4 acc1 = {0.f, 0.f, 0.f, 0.f};

        // x-part MFMAs before the poll (no dependency on flags)
        if (layer == 0) {
            bf8 xh, xl;
            split8(xv, xh, xl);
            acc0 = MFMA(xh, wh[0][4], acc0); acc0 = MFMA(xh, wl[0][4], acc0);
            acc0 = MFMA(xl, wh[0][4], acc0);
            acc1 = MFMA(xh, wh[1][4], acc1); acc1 = MFMA(xh, wl[1][4], acc1);
            acc1 = MFMA(xl, wh[1][4], acc1);
        }

        // ---- poll (wave 0): 32 peer flags + 32 cross-layer slack flags ----
        if (w == 0) {
            const char* fp;
            int tgt;
            if (layer == 0) {
                fp  = (lane < 32 ? fA : fB) + (size_t)(grp * 32 + (lane & 31)) * 16;
                tgt = (lane < 32) ? t : (t - LAG);
            } else {
                fp  = (lane < 32 ? fB : fA) + (size_t)(grp * 32 + (lane & 31)) * 16;
                tgt = (lane < 32) ? t : (t + 1);
            }
            for (;;) {
                int f = (int)ld_flag(fp);
                if (__all(f >= tgt)) break;
                __builtin_amdgcn_s_sleep(1);
            }
        }
        __syncthreads();

        // ---- h MFMAs ----
        if (layer == 0) {
            if (t >= 1) {
                const char* h1r = h1base + (size_t)(((t - 1) & sm) * 4 + grp) * 65536;
                #pragma unroll
                for (int c = 0; c < 4; ++c) {
                    const char* p = h1r + (size_t)(w * 4 + c) * 2048 + lane * 32;
                    bf8 hh = load_h(p), hl = load_h(p + 16);
                    acc0 = MFMA(hh, wh[0][c], acc0); acc0 = MFMA(hh, wl[0][c], acc0);
                    acc0 = MFMA(hl, wh[0][c], acc0);
                    acc1 = MFMA(hh, wh[1][c], acc1); acc1 = MFMA(hh, wl[1][c], acc1);
                    acc1 = MFMA(hl, wh[1][c], acc1);
                }
            }
        } else {
            {
                const char* h1r = h1base + (size_t)((t & sm) * 4 + grp) * 65536;
                #pragma unroll
                for (int c = 0; c < 4; ++c) {
                    const char* p = h1r + (size_t)(w * 4 + c) * 2048 + lane * 32;
                    bf8 hh = load_h(p), hl = load_h(p + 16);
                    acc0 = MFMA(hh, wh[0][c], acc0); acc0 = MFMA(hh, wl[0][c], acc0);
                    acc0 = MFMA(hl, wh[0][c], acc0);
                    acc1 = MFMA(hh, wh[1][c], acc1); acc1 = MFMA(hh, wl[1][c], acc1);
                    acc1 = MFMA(hl, wh[1][c], acc1);
                }
            }
            if (t >= 1) {
                const char* h2r = h2base + (size_t)(((t - 1) & sm) * 4 + grp) * 65536;
                #pragma unroll
                for (int c = 0; c < 4; ++c) {
                    const char* p = h2r + (size_t)(w * 4 + c) * 2048 + lane * 32;
                    bf8 hh = load_h(p), hl = load_h(p + 16);
                    acc0 = MFMA(hh, wh[0][4 + c], acc0); acc0 = MFMA(hh, wl[0][4 + c], acc0);
                    acc0 = MFMA(hl, wh[0][4 + c], acc0);
                    acc1 = MFMA(hh, wh[1][4 + c], acc1); acc1 = MFMA(hh, wl[1][4 + c], acc1);
                    acc1 = MFMA(hl, wh[1][4 + c], acc1);
                }
            }
        }

        // ---- partials: stride-18 (2-way banks) ----
        #pragma unroll
        for (int r = 0; r < 4; ++r) {
            shmem[(w * 2 + 0) * 288 + (kg * 4 + r) * 18 + col] = acc0[r];
            shmem[(w * 2 + 1) * 288 + (kg * 4 + r) * 18 + col] = acc1[r];
        }
        __syncthreads();

        // ---- reduce over 8 waves + bias + tanh + split -> staging ----
        {
            float s = bsum;
            #pragma unroll
            for (int wv = 0; wv < 8; ++wv)
                s += shmem[(wv * 2 + n_) * 288 + eb * 18 + ekk];
            const float val = tanhf(s);
            const unsigned short hi = f2bf(val);
            const unsigned short lo = f2bf(val - bf2f(hi));
            *(unsigned short*)(staging + stg)      = hi;
            *(unsigned short*)(staging + stg + 16) = lo;
        }
        __syncthreads();

        // ---- coalesced 2KB chunk store (128 x 16B, sc1) ----
        {
            char* hw = (layer ? h2base : h1base)
                     + (size_t)((t & sm) * 4 + grp) * 65536 + (size_t)slot * 2048;
            if (tid < 128) {
                const char* src = staging + tid * 16;
                store_h16(hw + tid * 16, *(const u64*)src, *(const u64*)(src + 8));
            }
        }
        asm volatile("s_waitcnt vmcnt(0)" ::: "memory");
        __syncthreads();
        if (tid == 0)
            st_flag((layer ? fB : fA) + (size_t)(grp * 32 + slot) * 16, (unsigned)(t + 1));

        // ---- x prefetch for t+1 (hides under next poll) ----
        if (layer == 0 && t + 1 < TT)
            ld8(xv, x + ((size_t)(b0 + col) * TT + (t + 1)) * II + (w * 32 + kg * 8));
    }

    // ---- FC gate: all 128 L1 flags >= TT, fence, then FC ----
    if (tid < 128) {
        while ((int)ld_flag(fB + (size_t)tid * 16) < TT)
            __builtin_amdgcn_s_sleep(2);
    }
    __syncthreads();
    acquire_fence();

    // FC: block computes out[:, 2*bid .. 2*bid+1]; h2(TT-1) at slot (TT-1)&sm
    float* Wlds = shmem + 2560;
    ((float4*)Wlds)[tid] = ((const float4*)(Wfc + (size_t)(2 * bid) * HH))[tid];
    __syncthreads();

    float p0 = 0.f, p1 = 0.f;
    {
        const int gr   = lane >> 4;
        const int bsub = lane & 15;
        const char* hb = h2base + (size_t)(((TT - 1) & sm) * 4 + gr) * 65536;
        #pragma unroll 4
        for (int k8 = w * 16; k8 < w * 16 + 16; ++k8) {
            const char* p = hb + (size_t)(k8 >> 2) * 2048
                          + (size_t)(bsub + ((k8 & 3) << 4)) * 32;
            bf8 hi = load_h(p), lo = load_h(p + 16);
            const int kb = k8 * 8;
            #pragma unroll
            for (int j = 0; j < 8; ++j) {
                float f = bf2f((unsigned short)hi[j]) + bf2f((unsigned short)lo[j]);
                p0 += f * Wlds[kb + j];
                p1 += f * Wlds[1024 + kb + j];
            }
        }
    }
    __syncthreads();
    shmem[(w * 64 + lane) * 2 + 0] = p0;
    shmem[(w * 64 + lane) * 2 + 1] = p1;
    __syncthreads();
    if (w < 2) {
        float s = bfc[2 * bid + w];
        #pragma unroll
        for (int j = 0; j < 8; ++j) s += shmem[(j * 64 + lane) * 2 + w];
        out[(size_t)lane * OO + 2 * bid + w] = s;
    }
}

extern "C" void kernel_launch(void* const* d_in, const int* in_sizes, int n_in,
                              void* d_out, int out_size, void* d_ws, size_t ws_size,
                              hipStream_t stream) {
    const float* x    = (const float*)d_in[0];
    const float* Wih0 = (const float*)d_in[1];
    const float* Whh0 = (const float*)d_in[2];
    const float* bih0 = (const float*)d_in[3];
    const float* bhh0 = (const float*)d_in[4];
    const float* Wih1 = (const float*)d_in[5];
    const float* Whh1 = (const float*)d_in[6];
    const float* bih1 = (const float*)d_in[7];
    const float* bhh1 = (const float*)d_in[8];
    const float* Wfc  = (const float*)d_in[9];
    const float* bfc  = (const float*)d_in[10];
    float* out = (float*)d_out;
    float* ws  = (float*)d_ws;

    // Ring depth from ws_size (never assume workspace — R1 lesson):
    // depth 64 needs 4KB flags + 2*64*4*64KB = ~33.6MB; else proven depth 32.
    int depth = (ws_size >= (size_t)4096 + (size_t)2 * 64 * 4 * 65536) ? 64 : 32;
    int sm  = depth - 1;
    int fpm = depth / 2 - 1;

    // zero both flag arrays every call (replay-safe)
    hipMemsetAsync(d_ws, 0, 4096, stream);

    void* args[] = { (void*)&x,
                     (void*)&Wih0, (void*)&Whh0, (void*)&bih0, (void*)&bhh0,
                     (void*)&Wih1, (void*)&Whh1, (void*)&bih1, (void*)&bhh1,
                     (void*)&Wfc,  (void*)&bfc,  (void*)&out,  (void*)&ws,
                     (void*)&sm,   (void*)&fpm };
    hipLaunchCooperativeKernel((void*)rnn_lag2, dim3(256), dim3(512),
                               args, 0, stream);
}

// Round 16
// 2290.518 us; speedup vs baseline: 4.6042x; 1.0540x over previous
//
#include <hip/hip_runtime.h>
#include <cmath>

#define BB 64
#define TT 512
#define II 256
#define HH 1024
#define OO 512
#define LAG 24

typedef short bf8 __attribute__((ext_vector_type(8)));
typedef float f32x4 __attribute__((ext_vector_type(4)));
typedef unsigned long long u64;

#define MFMA(a, b, c) __builtin_amdgcn_mfma_f32_16x16x32_bf16((a), (b), (c), 0, 0, 0)

__device__ __forceinline__ unsigned short f2bf(float f) {
    unsigned u = __float_as_uint(f);
    return (unsigned short)((u + 0x7fffu + ((u >> 16) & 1u)) >> 16);
}
__device__ __forceinline__ float bf2f(unsigned short h) {
    return __uint_as_float((unsigned)h << 16);
}
__device__ __forceinline__ void split8(const float* v, bf8& hi, bf8& lo) {
#pragma unroll
    for (int j = 0; j < 8; ++j) {
        unsigned short h = f2bf(v[j]);
        float r = v[j] - bf2f(h);
        hi[j] = (short)h;
        lo[j] = (short)f2bf(r);
    }
}
__device__ __forceinline__ void ld8(float* v, const float* p) {
    *(float4*)v       = *(const float4*)p;
    *(float4*)(v + 4) = *(const float4*)(p + 4);
}
// Consumer h loads: plain cached (L2 merges redundant reads) — R12/R13 proven.
__device__ __forceinline__ bf8 load_h(const void* p) { return *(const bf8*)p; }
// Producer stores: sc1 write-through, coalesced 16B — R13 proven.
__device__ __forceinline__ void store_h16(void* p, u64 a, u64 b) {
    __hip_atomic_store((u64*)p, a, __ATOMIC_RELAXED, __HIP_MEMORY_SCOPE_AGENT);
    __hip_atomic_store((u64*)((char*)p + 8), b, __ATOMIC_RELAXED, __HIP_MEMORY_SCOPE_AGENT);
}
__device__ __forceinline__ unsigned ld_flag(const void* p) {
    return __hip_atomic_load((const unsigned*)p, __ATOMIC_RELAXED, __HIP_MEMORY_SCOPE_AGENT);
}
__device__ __forceinline__ void st_flag(void* p, unsigned v) {
    __hip_atomic_store((unsigned*)p, v, __ATOMIC_RELAXED, __HIP_MEMORY_SCOPE_AGENT);
}
__device__ __forceinline__ void acquire_fence() {
    __builtin_amdgcn_fence(__ATOMIC_ACQUIRE, "agent");
    asm volatile("" ::: "memory");
}

// h layout per (layer, slot, group) 64KB: 32 K-chunks x 64 lanes x (16B hi+16B lo).
// h[b][k]: chunk k>>5, lane (b&15)+16*((k&31)>>3), j=k&7: hi j*2, lo j*2+16.
//
// R15 structure; ring depth & fence period runtime (sm = depth-1, fpm).
// Staleness: a consumer re-reads an address only after depth own-steps with
// >=2 own fences (period depth/2) in between; LAG < depth-2.
// L0-WG step t: h1(t); waits fA>=t (peers) & fB>=t-LAG (backpressure).
// L1-WG step t: h2(t); SPLIT polls: fA>=t+1 (h1(t), L0 ahead -> cheap), do
// Wih1 part, then fB>=t (peers), do Whh1 part. Deadlock-free as R14.
__global__ __launch_bounds__(512, 1) void rnn_lag3(
    const float* __restrict__ x,
    const float* __restrict__ Wih0, const float* __restrict__ Whh0,
    const float* __restrict__ bih0, const float* __restrict__ bhh0,
    const float* __restrict__ Wih1, const float* __restrict__ Whh1,
    const float* __restrict__ bih1, const float* __restrict__ bhh1,
    const float* __restrict__ Wfc,  const float* __restrict__ bfc,
    float* __restrict__ out, float* __restrict__ ws,
    int sm, int fpm)
{
    // partials [8 waves][2 tiles][16][18] = 4608 fl (stride 18: 2-way banks, free)
    // staging at +4608 (512 fl). FC reuses [2560,4608) for Wfc rows.
    __shared__ float shmem[5120];
    char* staging = (char*)(shmem + 4608);

    const int tid  = threadIdx.x;
    const int w    = tid >> 6;
    const int lane = tid & 63;
    const int col  = lane & 15;
    const int kg   = lane >> 4;
    const int bid  = blockIdx.x;
    const int grp   = bid & 3;
    const int layer = (bid >> 2) & 1;
    const int slot  = bid >> 3;        // 0..31
    const int rb    = slot * 32;
    const int b0    = grp * 16;

    char* wsB    = (char*)ws;
    char* fA     = wsB;                // 128 x 16B (L0 flags)
    char* fB     = wsB + 2048;         // 128 x 16B (L1 flags)
    char* h1base = wsB + 4096;         // [depth slot][4 grp] 64KB
    char* h2base = h1base + (size_t)(sm + 1) * 4 * 65536;

    // ---- weight preload (VGPR) — identical R14/R15 ----
    bf8 wh[2][8], wl[2][8];
    {
        float v[8];
        if (layer == 0) {
            #pragma unroll
            for (int n = 0; n < 2; ++n) {
                ld8(v, Wih0 + (size_t)(rb + n * 16 + col) * II + (w * 32 + kg * 8));
                split8(v, wh[n][4], wl[n][4]);
                #pragma unroll
                for (int c = 0; c < 4; ++c) {
                    ld8(v, Whh0 + (size_t)(rb + n * 16 + col) * HH + ((w * 4 + c) * 32 + kg * 8));
                    split8(v, wh[n][c], wl[n][c]);
                }
            }
        } else {
            #pragma unroll
            for (int n = 0; n < 2; ++n)
                #pragma unroll
                for (int c = 0; c < 4; ++c) {
                    ld8(v, Wih1 + (size_t)(rb + n * 16 + col) * HH + ((w * 4 + c) * 32 + kg * 8));
                    split8(v, wh[n][c], wl[n][c]);
                    ld8(v, Whh1 + (size_t)(rb + n * 16 + col) * HH + ((w * 4 + c) * 32 + kg * 8));
                    split8(v, wh[n][4 + c], wl[n][4 + c]);
                }
        }
    }

    // ---- epilogue role: one thread per output element (2 tiles x 16 x 16) ----
    const int n_  = tid >> 8;
    const int ekk = (tid >> 4) & 15;
    const int eb  = tid & 15;
    const int R   = rb + n_ * 16 + ekk;
    const float bsum = layer ? (bih1[R] + bhh1[R]) : (bih0[R] + bhh0[R]);
    const int kk5 = n_ * 16 + ekk;
    const int stg = (eb + 16 * (kk5 >> 3)) * 32 + (kk5 & 7) * 2;

    acquire_fence();   // kill stale lines from a previous graph replay

    float xv[8];
    if (layer == 0)
        ld8(xv, x + (size_t)(b0 + col) * TT * II + (w * 32 + kg * 8));

    for (int t = 0; t < TT; ++t) {
        if ((t & fpm) == 0) acquire_fence();

        f32x4 acc0 = {0.f, 0.f, 0.f, 0.f};
        f32x4 acc1 = {0.f, 0.f, 0.f, 0.f};

        if (layer == 0) {
            // x-part MFMAs before the poll (no dependency on flags)
            bf8 xh, xl;
            split8(xv, xh, xl);
            acc0 = MFMA(xh, wh[0][4], acc0); acc0 = MFMA(xh, wl[0][4], acc0);
            acc0 = MFMA(xl, wh[0][4], acc0);
            acc1 = MFMA(xh, wh[1][4], acc1); acc1 = MFMA(xh, wl[1][4], acc1);
            acc1 = MFMA(xl, wh[1][4], acc1);

            // poll: fA>=t (peers, lanes 0-31) & fB>=t-LAG (backpressure, 32-63)
            if (w == 0) {
                const char* fp = (lane < 32 ? fA : fB)
                               + (size_t)(grp * 32 + (lane & 31)) * 16;
                const int tgt = (lane < 32) ? t : (t - LAG);
                for (;;) {
                    int f = (int)ld_flag(fp);
                    if (__all(f >= tgt)) break;
                }
            }
            __syncthreads();

            if (t >= 1) {
                const char* h1r = h1base + (size_t)(((t - 1) & sm) * 4 + grp) * 65536;
                #pragma unroll
                for (int c = 0; c < 4; ++c) {
                    const char* p = h1r + (size_t)(w * 4 + c) * 2048 + lane * 32;
                    bf8 hh = load_h(p), hl = load_h(p + 16);
                    acc0 = MFMA(hh, wh[0][c], acc0); acc0 = MFMA(hh, wl[0][c], acc0);
                    acc0 = MFMA(hl, wh[0][c], acc0);
                    acc1 = MFMA(hh, wh[1][c], acc1); acc1 = MFMA(hh, wl[1][c], acc1);
                    acc1 = MFMA(hl, wh[1][c], acc1);
                }
            }
        } else {
            // ---- phase 1: poll fA>=t+1 (h1(t); L0 runs ahead -> usually free) ----
            if (w == 0) {
                const char* fp = fA + (size_t)(grp * 32 + (lane & 31)) * 16;
                const int tgt = t + 1;
                for (;;) {
                    int f = (lane < 32) ? (int)ld_flag(fp) : tgt;
                    if (__all(f >= tgt)) break;
                }
            }
            __syncthreads();
            {
                const char* h1r = h1base + (size_t)((t & sm) * 4 + grp) * 65536;
                #pragma unroll
                for (int c = 0; c < 4; ++c) {
                    const char* p = h1r + (size_t)(w * 4 + c) * 2048 + lane * 32;
                    bf8 hh = load_h(p), hl = load_h(p + 16);
                    acc0 = MFMA(hh, wh[0][c], acc0); acc0 = MFMA(hh, wl[0][c], acc0);
                    acc0 = MFMA(hl, wh[0][c], acc0);
                    acc1 = MFMA(hh, wh[1][c], acc1); acc1 = MFMA(hh, wl[1][c], acc1);
                    acc1 = MFMA(hl, wh[1][c], acc1);
                }
            }
            // ---- phase 2: poll fB>=t (h2(t-1) peers), then Whh1 part ----
            if (t >= 1) {
                if (w == 0) {
                    const char* fp = fB + (size_t)(grp * 32 + (lane & 31)) * 16;
                    const int tgt = t;
                    for (;;) {
                        int f = (lane < 32) ? (int)ld_flag(fp) : tgt;
                        if (__all(f >= tgt)) break;
                    }
                }
                __syncthreads();
                const char* h2r = h2base + (size_t)(((t - 1) & sm) * 4 + grp) * 65536;
                #pragma unroll
                for (int c = 0; c < 4; ++c) {
                    const char* p = h2r + (size_t)(w * 4 + c) * 2048 + lane * 32;
                    bf8 hh = load_h(p), hl = load_h(p + 16);
                    acc0 = MFMA(hh, wh[0][4 + c], acc0); acc0 = MFMA(hh, wl[0][4 + c], acc0);
                    acc0 = MFMA(hl, wh[0][4 + c], acc0);
                    acc1 = MFMA(hh, wh[1][4 + c], acc1); acc1 = MFMA(hh, wl[1][4 + c], acc1);
                    acc1 = MFMA(hl, wh[1][4 + c], acc1);
                }
            }
        }

        // ---- partials: stride-18 (2-way banks) ----
        #pragma unroll
        for (int r = 0; r < 4; ++r) {
            shmem[(w * 2 + 0) * 288 + (kg * 4 + r) * 18 + col] = acc0[r];
            shmem[(w * 2 + 1) * 288 + (kg * 4 + r) * 18 + col] = acc1[r];
        }
        __syncthreads();

        // ---- reduce over 8 waves + bias + tanh + split -> staging ----
        {
            float s = bsum;
            #pragma unroll
            for (int wv = 0; wv < 8; ++wv)
                s += shmem[(wv * 2 + n_) * 288 + eb * 18 + ekk];
            const float val = tanhf(s);
            const unsigned short hi = f2bf(val);
            const unsigned short lo = f2bf(val - bf2f(hi));
            *(unsigned short*)(staging + stg)      = hi;
            *(unsigned short*)(staging + stg + 16) = lo;
        }
        __syncthreads();

        // ---- coalesced 2KB chunk store (128 x 16B, sc1) ----
        {
            char* hw = (layer ? h2base : h1base)
                     + (size_t)((t & sm) * 4 + grp) * 65536 + (size_t)slot * 2048;
            if (tid < 128) {
                const char* src = staging + tid * 16;
                store_h16(hw + tid * 16, *(const u64*)src, *(const u64*)(src + 8));
            }
        }
        asm volatile("s_waitcnt vmcnt(0)" ::: "memory");
        __syncthreads();
        if (tid == 0)
            st_flag((layer ? fB : fA) + (size_t)(grp * 32 + slot) * 16, (unsigned)(t + 1));

        // ---- x prefetch for t+1 (hides under next poll) ----
        if (layer == 0 && t + 1 < TT)
            ld8(xv, x + ((size_t)(b0 + col) * TT + (t + 1)) * II + (w * 32 + kg * 8));
    }

    // ---- FC gate: all 128 L1 flags >= TT, fence, then FC ----
    if (tid < 128) {
        while ((int)ld_flag(fB + (size_t)tid * 16) < TT)
            __builtin_amdgcn_s_sleep(2);
    }
    __syncthreads();
    acquire_fence();

    // FC: block computes out[:, 2*bid .. 2*bid+1]; h2(TT-1) at slot (TT-1)&sm
    float* Wlds = shmem + 2560;
    ((float4*)Wlds)[tid] = ((const float4*)(Wfc + (size_t)(2 * bid) * HH))[tid];
    __syncthreads();

    float p0 = 0.f, p1 = 0.f;
    {
        const int gr   = lane >> 4;
        const int bsub = lane & 15;
        const char* hb = h2base + (size_t)(((TT - 1) & sm) * 4 + gr) * 65536;
        #pragma unroll 4
        for (int k8 = w * 16; k8 < w * 16 + 16; ++k8) {
            const char* p = hb + (size_t)(k8 >> 2) * 2048
                          + (size_t)(bsub + ((k8 & 3) << 4)) * 32;
            bf8 hi = load_h(p), lo = load_h(p + 16);
            const int kb = k8 * 8;
            #pragma unroll
            for (int j = 0; j < 8; ++j) {
                float f = bf2f((unsigned short)hi[j]) + bf2f((unsigned short)lo[j]);
                p0 += f * Wlds[kb + j];
                p1 += f * Wlds[1024 + kb + j];
            }
        }
    }
    __syncthreads();
    shmem[(w * 64 + lane) * 2 + 0] = p0;
    shmem[(w * 64 + lane) * 2 + 1] = p1;
    __syncthreads();
    if (w < 2) {
        float s = bfc[2 * bid + w];
        #pragma unroll
        for (int j = 0; j < 8; ++j) s += shmem[(j * 64 + lane) * 2 + w];
        out[(size_t)lane * OO + 2 * bid + w] = s;
    }
}

extern "C" void kernel_launch(void* const* d_in, const int* in_sizes, int n_in,
                              void* d_out, int out_size, void* d_ws, size_t ws_size,
                              hipStream_t stream) {
    const float* x    = (const float*)d_in[0];
    const float* Wih0 = (const float*)d_in[1];
    const float* Whh0 = (const float*)d_in[2];
    const float* bih0 = (const float*)d_in[3];
    const float* bhh0 = (const float*)d_in[4];
    const float* Wih1 = (const float*)d_in[5];
    const float* Whh1 = (const float*)d_in[6];
    const float* bih1 = (const float*)d_in[7];
    const float* bhh1 = (const float*)d_in[8];
    const float* Wfc  = (const float*)d_in[9];
    const float* bfc  = (const float*)d_in[10];
    float* out = (float*)d_out;
    float* ws  = (float*)d_ws;

    // Ring depth from ws_size (never assume workspace — R1 lesson):
    // depth d needs 4KB + 2*d*4*64KB. 128 -> 67.1MB, 64 -> 33.6MB (proven R15).
    int depth = 32;
    if (ws_size >= (size_t)4096 + (size_t)2 * 128 * 4 * 65536)      depth = 128;
    else if (ws_size >= (size_t)4096 + (size_t)2 * 64 * 4 * 65536)  depth = 64;
    int sm  = depth - 1;
    int fpm = depth / 2 - 1;

    // zero both flag arrays every call (replay-safe)
    hipMemsetAsync(d_ws, 0, 4096, stream);

    void* args[] = { (void*)&x,
                     (void*)&Wih0, (void*)&Whh0, (void*)&bih0, (void*)&bhh0,
                     (void*)&Wih1, (void*)&Whh1, (void*)&bih1, (void*)&bhh1,
                     (void*)&Wfc,  (void*)&bfc,  (void*)&out,  (void*)&ws,
                     (void*)&sm,   (void*)&fpm };
    hipLaunchCooperativeKernel((void*)rnn_lag3, dim3(256), dim3(512),
                               args, 0, stream);
}